// Round 2
// baseline (116.446 us; speedup 1.0000x reference)
//
#include <hip/hip_runtime.h>

#define BATCH 65536
#define IN_DIM 128
#define INT_NODES 255
#define LEAF 256
#define OUT_DIM 8
#define AMB_TH 1.5e-3f  // fp16-GEMM z error ~3e-4 RMS; ~5-sigma guard band

typedef float    f4v __attribute__((ext_vector_type(4)));
typedef _Float16 h8v __attribute__((ext_vector_type(8)));
typedef _Float16 h2v __attribute__((ext_vector_type(2)));

#define LGKM0() __asm__ volatile("s_waitcnt lgkmcnt(0)" ::: "memory")

// Static module scratch (580 KB). The harness re-poisons the 256 MiB d_ws
// arena unconditionally (R1 experiment: not using d_ws changed nothing), so
// static memory is kept purely for simplicity. prep() fully rewrites these
// every launch.
__device__ __align__(16) _Float16 g_Wh[LEAF * 1024];  // 512 KB fp16 Wor_t
__device__ __align__(16) _Float16 g_Bf[32768];        // 64 KB Wp B-frags
__device__ __align__(16) _Float16 g_Bb[2048];         // 4 KB bor B-frag

__device__ __forceinline__ float fdot2(h2v a, h2v b, float c) {
#if __has_builtin(__builtin_amdgcn_fdot2)
    return __builtin_amdgcn_fdot2(a, b, c, false);
#else
    return c + (float)a[0] * (float)b[0] + (float)a[1] * (float)b[1];
#endif
}

// Prepass: blocks [0,64) LDS-tiled transpose Wor -> g_Wh fp16 [l][o*128+i];
// blocks [64,192) Wp -> fp16 B-frags; blocks [192,200) bor -> fp16 B-frag.
__global__ __launch_bounds__(256) void prep(const float* __restrict__ Wor,
                                            const float* __restrict__ Wp,
                                            const float* __restrict__ bor) {
    if (blockIdx.x < 64) {
        __shared__ float t[64][65];
        const int rt = blockIdx.x >> 2, ct = blockIdx.x & 3;  // 16 x 4 tiles of 64x64
        const int r0 = rt * 64, c0 = ct * 64;
        const int tx = threadIdx.x & 63, ty = threadIdx.x >> 6;
#pragma unroll
        for (int p = 0; p < 16; ++p) {
            int r = ty + p * 4;
            t[r][tx] = Wor[(size_t)(r0 + r) * 256 + c0 + tx];     // coalesced
        }
        __syncthreads();
#pragma unroll
        for (int p = 0; p < 16; ++p) {
            int r = ty + p * 4;
            g_Wh[(size_t)(c0 + r) * 1024 + r0 + tx] = (_Float16)t[tx][r];  // coalesced
        }
    } else if (blockIdx.x < 192) {
        // B-frag (16x16x32): B[k=ks*32+(lane>>4)*8+j][n=ntg*16+(lane&15)],
        // slot = ((ks*16+ntg)*64+lane)*8+j.
        int slot = (blockIdx.x - 64) * 256 + threadIdx.x;   // 32768
        int j    = slot & 7;
        int lane = (slot >> 3) & 63;
        int ntg  = (slot >> 9) & 15;
        int ks   = slot >> 13;
        int n = ntg * 16 + (lane & 15);
        int k = ks * 32 + (lane >> 4) * 8 + j;
        float v = (n < INT_NODES) ? Wp[n * IN_DIM + k] : 0.f;
        g_Bf[slot] = (_Float16)v;
    } else {
        // bor B-frag: one 16-col tile (cols 0..7 = outputs), slot=(ks*64+lane)*8+j
        int slot = (blockIdx.x - 192) * 256 + threadIdx.x;  // 2048
        int j    = slot & 7;
        int lane = (slot >> 3) & 63;
        int ks   = slot >> 9;
        int o = lane & 15;
        int k = ks * 32 + (lane >> 4) * 8 + j;
        float v = (o < OUT_DIM) ? bor[o * IN_DIM + k] : 0.f;
        g_Bb[slot] = (_Float16)v;
    }
}

// Zero-barrier fused main. Wave = 32 rows x 256 nodes (2 row-groups share
// every B-fragment load -> half the L2 B-traffic per row vs 16-row waves).
// Wave-private LDS, lgkmcnt-only ordering.
__global__ __launch_bounds__(256) void dgt_main(
    const float* __restrict__ x, const float* __restrict__ Wp,
    const float* __restrict__ bp, const float* __restrict__ stds,
    float* __restrict__ out, float* __restrict__ stdo) {

    __shared__ unsigned char sgnS[4][LEAF * 8];  // [wave][n*8+rg]: codes rows rg*4+rr
    __shared__ float asumS[4][32 * 16];          // [wave][row*16 + c]
    __shared__ float hdS[4][32 * 36];            // [wave][r*36 + o*4 + kq]
    __shared__ float tbS[4][32 * 8];             // [wave][r*8 + o]: <bor,x>
    __shared__ float psS[4][32];
    __shared__ int   lfS[4][32];

    const int tid  = threadIdx.x;
    const int wave = tid >> 6;
    const int lane = tid & 63;
    const int c = lane & 15;
    const int g = lane >> 4;
    const int rowbase = blockIdx.x * 128 + wave * 32;

    unsigned char* sgn = sgnS[wave];
    float* asum = asumS[wave];
    float* hd = hdS[wave];

    // ---- A-fragments, 2 row-groups x 4 k-steps (32 VGPRs) ----
    h8v ah[2][4];
#pragma unroll
    for (int rg = 0; rg < 2; ++rg) {
        const float* xb = x + (size_t)(rowbase + rg * 16 + c) * IN_DIM;
#pragma unroll
        for (int ks = 0; ks < 4; ++ks) {
            const float* p = xb + ks * 32 + g * 8;
            float4 v0 = *reinterpret_cast<const float4*>(p);
            float4 v1 = *reinterpret_cast<const float4*>(p + 4);
            h8v a;
            a[0] = (_Float16)v0.x; a[1] = (_Float16)v0.y;
            a[2] = (_Float16)v0.z; a[3] = (_Float16)v0.w;
            a[4] = (_Float16)v1.x; a[5] = (_Float16)v1.y;
            a[6] = (_Float16)v1.z; a[7] = (_Float16)v1.w;
            ah[rg][ks] = a;
        }
    }

    // ---- bor head via MFMA (leaf-independent; Bb loads shared by both rg) ----
    {
        const h8v* Bb8 = (const h8v*)g_Bb;
        f4v tb0 = (f4v){0.f, 0.f, 0.f, 0.f};
        f4v tb1 = (f4v){0.f, 0.f, 0.f, 0.f};
#pragma unroll
        for (int ks = 0; ks < 4; ++ks) {
            h8v b = Bb8[ks * 64 + lane];
            tb0 = __builtin_amdgcn_mfma_f32_16x16x32_f16(ah[0][ks], b, tb0, 0, 0, 0);
            tb1 = __builtin_amdgcn_mfma_f32_16x16x32_f16(ah[1][ks], b, tb1, 0, 0, 0);
        }
        if (c < OUT_DIM) {
#pragma unroll
            for (int rr = 0; rr < 4; ++rr) {
                tbS[wave][(g * 4 + rr) * 8 + c]        = tb0[rr];
                tbS[wave][(16 + g * 4 + rr) * 8 + c]   = tb1[rr];
            }
        }
    }

    // ---- GEMM + compress, two 128-col halves; each B load feeds 2 MFMAs ----
    const h8v* Bf8 = (const h8v*)g_Bf;
    float pp[2][4];
#pragma unroll
    for (int rg = 0; rg < 2; ++rg)
#pragma unroll
        for (int rr = 0; rr < 4; ++rr) pp[rg][rr] = 0.f;
#pragma unroll
    for (int h = 0; h < 2; ++h) {
        f4v acc[2][8];
#pragma unroll
        for (int rg = 0; rg < 2; ++rg)
#pragma unroll
            for (int nt = 0; nt < 8; ++nt) acc[rg][nt] = (f4v){0.f, 0.f, 0.f, 0.f};
#pragma unroll
        for (int ks = 0; ks < 4; ++ks)
#pragma unroll
            for (int nt = 0; nt < 8; ++nt) {
                h8v b = Bf8[(ks * 16 + h * 8 + nt) * 64 + lane];  // coalesced, L2-hot
                acc[0][nt] = __builtin_amdgcn_mfma_f32_16x16x32_f16(ah[0][ks], b, acc[0][nt], 0, 0, 0);
                acc[1][nt] = __builtin_amdgcn_mfma_f32_16x16x32_f16(ah[1][ks], b, acc[1][nt], 0, 0, 0);
            }
        // compress: C/D col n = h*128 + nt*16 + c, row m = rg*16 + g*4 + rr.
        // Col 255 is zero-padded in g_Bf -> z=0 contributes 0 to the abs-sum,
        // so no n-guard needed on the accumulation (only on the bp read).
#pragma unroll
        for (int nt = 0; nt < 8; ++nt) {
            const int n = h * 128 + nt * 16 + c;
            const float bpv = (n < INT_NODES) ? bp[n] : 0.f;   // 1KB, L1-hot
#pragma unroll
            for (int rg = 0; rg < 2; ++rg) {
                unsigned by = 0;
#pragma unroll
                for (int rr = 0; rr < 4; ++rr) {
                    float v = acc[rg][nt][rr] + bpv;
                    float av = fabsf(v);
                    pp[rg][rr] += av;
                    by |= ((v < 0.f ? 1u : 0u) | (av < AMB_TH ? 2u : 0u)) << (2 * rr);
                }
                sgn[n * 8 + rg * 4 + g] = (unsigned char)by;
            }
        }
    }
#pragma unroll
    for (int rg = 0; rg < 2; ++rg)
#pragma unroll
        for (int rr = 0; rr < 4; ++rr)
            asum[(rg * 16 + g * 4 + rr) * 16 + c] = pp[rg][rr];

    // ---- heads-x prefetch, both row-halves (leaf-independent; overlaps
    //      the traversal latency chain). 32 VGPRs. ----
    h2v xh[2][16];
#pragma unroll
    for (int rh = 0; rh < 2; ++rh) {
        const float* xr = x + (size_t)(rowbase + rh * 16 + (lane >> 2)) * IN_DIM;
        const int kq = lane & 3;
#pragma unroll
        for (int ch = 0; ch < 4; ++ch) {
            const int base = (ch * 4 + kq) * 8;
            float4 v0 = *reinterpret_cast<const float4*>(xr + base);
            float4 v1 = *reinterpret_cast<const float4*>(xr + base + 4);
            xh[rh][ch * 4 + 0] = (h2v){(_Float16)v0.x, (_Float16)v0.y};
            xh[rh][ch * 4 + 1] = (h2v){(_Float16)v0.z, (_Float16)v0.w};
            xh[rh][ch * 4 + 2] = (h2v){(_Float16)v1.x, (_Float16)v1.y};
            xh[rh][ch * 4 + 3] = (h2v){(_Float16)v1.z, (_Float16)v1.w};
        }
    }
    LGKM0();   // sgn/asum/tb visible (same wave)

    // ---- traversal + p*: lanes 0..31, one row each ----
    if (lane < 32) {
        const int r = lane;
        float s = 0.f;
#pragma unroll
        for (int cc = 0; cc < 16; cc += 4) {
            f4v v = *reinterpret_cast<f4v*>(&asum[r * 16 + cc]);
            s += (v[0] + v[1]) + (v[2] + v[3]);
        }
        const float fac = s * (1.0f / (float)INT_NODES);
        // p* of argmax leaf: sum_l exp(and_z_l - 8 fac) = (1 + e^{-2 fac})^8.
        const float e = expf(-2.0f * fac);
        const float q = 1.0f + e;
        const float q2 = q * q, q4 = q2 * q2, q8 = q4 * q4;

        int node = 0;
#pragma unroll
        for (int d = 0; d < 8; ++d) {
            unsigned by = sgn[node * 8 + (r >> 2)];
            int code = (int)((by >> ((r & 3) * 2)) & 3u);
            int neg;
            if (code & 2) {          // ~1% of rows: exact sign via fp64, 4 chains
                const float* wr = Wp + node * IN_DIM;
                const float* xrow = x + (size_t)(rowbase + r) * IN_DIM;
                double z0 = 0.0, z1 = 0.0, z2 = 0.0, z3 = 0.0;
                for (int k = 0; k < IN_DIM; k += 4) {
                    float4 wv = *reinterpret_cast<const float4*>(wr + k);
                    float4 xv = *reinterpret_cast<const float4*>(xrow + k);
                    z0 = fma((double)wv.x, (double)xv.x, z0);
                    z1 = fma((double)wv.y, (double)xv.y, z1);
                    z2 = fma((double)wv.z, (double)xv.z, z2);
                    z3 = fma((double)wv.w, (double)xv.w, z3);
                }
                double zd = ((z0 + z1) + (z2 + z3)) + (double)bp[node];
                neg = (zd < 0.0) ? 1 : 0;
            } else {
                neg = code & 1;
            }
            node = 2 * node + 1 + neg;
        }
        psS[wave][r] = 1.0f / q8;
        lfS[wave][r] = node - INT_NODES;
    }
    LGKM0();

    // ---- heads: lane = (row r, K-quarter kq); fp16 gather + fdot2, two
    //      row-halves. Chunk (ch*4+kq): 4 kq lanes cover one 64B line. ----
#pragma unroll
    for (int rh = 0; rh < 2; ++rh) {
        const int r = rh * 16 + (lane >> 2), kq = lane & 3;
        const int leaf = lfS[wave][r];
        const _Float16* wl = g_Wh + (size_t)leaf * 1024;
        float hp[8];
#pragma unroll
        for (int o = 0; o < 8; ++o) hp[o] = 0.f;
#pragma unroll
        for (int ch = 0; ch < 4; ++ch) {
            const int base = (ch * 4 + kq) * 8;
            h2v x0 = xh[rh][ch * 4 + 0], x1 = xh[rh][ch * 4 + 1];
            h2v x2 = xh[rh][ch * 4 + 2], x3 = xh[rh][ch * 4 + 3];
#pragma unroll
            for (int o = 0; o < 8; ++o) {
                h8v w8 = *reinterpret_cast<const h8v*>(wl + o * IN_DIM + base);
                h2v w0 = {w8[0], w8[1]}, w1 = {w8[2], w8[3]};
                h2v w2 = {w8[4], w8[5]}, w3 = {w8[6], w8[7]};
                hp[o] = fdot2(w0, x0, hp[o]);
                hp[o] = fdot2(w1, x1, hp[o]);
                hp[o] = fdot2(w2, x2, hp[o]);
                hp[o] = fdot2(w3, x3, hp[o]);
            }
        }
#pragma unroll
        for (int o = 0; o < 8; ++o)
            hd[r * 36 + o * 4 + kq] = hp[o];
    }
    LGKM0();

    // ---- final reduce + stores: lane = (row r, o-pair op), two halves ----
#pragma unroll
    for (int rh = 0; rh < 2; ++rh) {
        const int r = rh * 16 + (lane >> 2), op = lane & 3, o0 = op * 2;
        const float ps = psS[wave][r];
        f4v a = *reinterpret_cast<f4v*>(&hd[r * 36 + o0 * 4]);
        f4v b = *reinterpret_cast<f4v*>(&hd[r * 36 + o0 * 4 + 4]);
        float2 ov;
        ov.x = ps * ((a[0] + a[1]) + (a[2] + a[3])) + tbS[wave][r * 8 + o0];
        ov.y = ps * ((b[0] + b[1]) + (b[2] + b[3])) + tbS[wave][r * 8 + o0 + 1];
        const size_t ob = (size_t)(rowbase + r) * OUT_DIM + o0;
        *reinterpret_cast<float2*>(out + ob) = ov;
        const int leaf = lfS[wave][r];
        float2 sv;
        sv.x = fminf(fmaxf(ps * stds[leaf * OUT_DIM + o0],     -20.0f), 2.0f);
        sv.y = fminf(fmaxf(ps * stds[leaf * OUT_DIM + o0 + 1], -20.0f), 2.0f);
        *reinterpret_cast<float2*>(stdo + ob) = sv;
    }
}

extern "C" void kernel_launch(void* const* d_in, const int* in_sizes, int n_in,
                              void* d_out, int out_size, void* d_ws, size_t ws_size,
                              hipStream_t stream) {
    const float* x    = (const float*)d_in[0];
    const float* Wp   = (const float*)d_in[1];
    const float* bp   = (const float*)d_in[2];
    // d_in[3] = Wand -- folded into the traversal, unused.
    const float* Wor  = (const float*)d_in[4];
    const float* bor  = (const float*)d_in[5];
    const float* stds = (const float*)d_in[6];
    float* out = (float*)d_out;
    (void)d_ws; (void)ws_size;  // ws poison is unconditional (R1); ws unused

    prep<<<200, 256, 0, stream>>>(Wor, Wp, bor);
    dgt_main<<<BATCH / 128, 256, 0, stream>>>(x, Wp, bp, stds,
                                              out, out + (size_t)BATCH * OUT_DIM);
}

// Round 3
// 112.486 us; speedup vs baseline: 1.0352x; 1.0352x over previous
//
#include <hip/hip_runtime.h>

#define BATCH 65536
#define IN_DIM 128
#define INT_NODES 255
#define LEAF 256
#define OUT_DIM 8
#define AMB_TH 1.5e-3f  // fp16-GEMM z error ~3e-4 RMS; ~5-sigma guard band

typedef float    f4v __attribute__((ext_vector_type(4)));
typedef _Float16 h8v __attribute__((ext_vector_type(8)));
typedef _Float16 h2v __attribute__((ext_vector_type(2)));

#define LGKM0() __asm__ volatile("s_waitcnt lgkmcnt(0)" ::: "memory")

// Static module scratch (580 KB). The harness re-poisons the 256 MiB d_ws
// arena unconditionally (R1 experiment), so d_ws is unused.
// prep() fully rewrites these buffers every launch.
// R2 lesson: 32-row waves (B-frag reuse) regressed — acc[2][8]+ah[2][4]
// pushed peak VGPR past 128, occupancy 4->3 waves/SIMD; the latency-bound
// zero-barrier structure values occupancy over L2 B-traffic. Keep 16-row.
__device__ __align__(16) _Float16 g_Wh[LEAF * 1024];  // 512 KB fp16 Wor_t
__device__ __align__(16) _Float16 g_Bf[32768];        // 64 KB Wp B-frags
__device__ __align__(16) _Float16 g_Bb[2048];         // 4 KB bor B-frag

__device__ __forceinline__ float fdot2(h2v a, h2v b, float c) {
#if __has_builtin(__builtin_amdgcn_fdot2)
    return __builtin_amdgcn_fdot2(a, b, c, false);
#else
    return c + (float)a[0] * (float)b[0] + (float)a[1] * (float)b[1];
#endif
}

// Prepass: blocks [0,64) LDS-tiled transpose Wor -> g_Wh fp16 [l][o*128+i];
// blocks [64,192) Wp -> fp16 B-frags; blocks [192,200) bor -> fp16 B-frag.
__global__ __launch_bounds__(256) void prep(const float* __restrict__ Wor,
                                            const float* __restrict__ Wp,
                                            const float* __restrict__ bor) {
    if (blockIdx.x < 64) {
        __shared__ float t[64][65];
        const int rt = blockIdx.x >> 2, ct = blockIdx.x & 3;  // 16 x 4 tiles of 64x64
        const int r0 = rt * 64, c0 = ct * 64;
        const int tx = threadIdx.x & 63, ty = threadIdx.x >> 6;
#pragma unroll
        for (int p = 0; p < 16; ++p) {
            int r = ty + p * 4;
            t[r][tx] = Wor[(size_t)(r0 + r) * 256 + c0 + tx];     // coalesced
        }
        __syncthreads();
#pragma unroll
        for (int p = 0; p < 16; ++p) {
            int r = ty + p * 4;
            g_Wh[(size_t)(c0 + r) * 1024 + r0 + tx] = (_Float16)t[tx][r];  // coalesced
        }
    } else if (blockIdx.x < 192) {
        // B-frag (16x16x32): B[k=ks*32+(lane>>4)*8+j][n=ntg*16+(lane&15)],
        // slot = ((ks*16+ntg)*64+lane)*8+j.
        int slot = (blockIdx.x - 64) * 256 + threadIdx.x;   // 32768
        int j    = slot & 7;
        int lane = (slot >> 3) & 63;
        int ntg  = (slot >> 9) & 15;
        int ks   = slot >> 13;
        int n = ntg * 16 + (lane & 15);
        int k = ks * 32 + (lane >> 4) * 8 + j;
        float v = (n < INT_NODES) ? Wp[n * IN_DIM + k] : 0.f;
        g_Bf[slot] = (_Float16)v;
    } else {
        // bor B-frag: one 16-col tile (cols 0..7 = outputs), slot=(ks*64+lane)*8+j
        int slot = (blockIdx.x - 192) * 256 + threadIdx.x;  // 2048
        int j    = slot & 7;
        int lane = (slot >> 3) & 63;
        int ks   = slot >> 9;
        int o = lane & 15;
        int k = ks * 32 + (lane >> 4) * 8 + j;
        float v = (o < OUT_DIM) ? bor[o * IN_DIM + k] : 0.f;
        g_Bb[slot] = (_Float16)v;
    }
}

// Zero-barrier fused main. Wave = 16 rows x 256 nodes, wave-private LDS,
// lgkmcnt-only ordering. fp16 GEMM + fp16 heads gather + bor head via MFMA.
__global__ __launch_bounds__(256) void dgt_main(
    const float* __restrict__ x, const float* __restrict__ Wp,
    const float* __restrict__ bp, const float* __restrict__ stds,
    float* __restrict__ out, float* __restrict__ stdo) {

    __shared__ unsigned char sgnS[4][LEAF * 4];  // [wave][n*4+g]: codes rows g*4+rr
    __shared__ float asumS[4][16 * 16];          // [wave][row*16 + c]
    __shared__ float hdS[4][16 * 36];            // [wave][r*36 + o*4 + kq]
    __shared__ float tbS[4][16 * 8];             // [wave][r*8 + o]: <bor,x>
    __shared__ float psS[4][16];
    __shared__ int   lfS[4][16];

    const int tid  = threadIdx.x;
    const int wave = tid >> 6;
    const int lane = tid & 63;
    const int c = lane & 15;
    const int g = lane >> 4;
    const int rowbase = blockIdx.x * 64 + wave * 16;

    unsigned char* sgn = sgnS[wave];
    float* asum = asumS[wave];
    float* hd = hdS[wave];

    // ---- A-fragments for all 4 k-steps (16 VGPRs) ----
    h8v ah[4];
    {
        const float* xb = x + (size_t)(rowbase + c) * IN_DIM;
#pragma unroll
        for (int ks = 0; ks < 4; ++ks) {
            const float* p = xb + ks * 32 + g * 8;
            float4 v0 = *reinterpret_cast<const float4*>(p);
            float4 v1 = *reinterpret_cast<const float4*>(p + 4);
            h8v a;
            a[0] = (_Float16)v0.x; a[1] = (_Float16)v0.y;
            a[2] = (_Float16)v0.z; a[3] = (_Float16)v0.w;
            a[4] = (_Float16)v1.x; a[5] = (_Float16)v1.y;
            a[6] = (_Float16)v1.z; a[7] = (_Float16)v1.w;
            ah[ks] = a;
        }
    }

    // ---- bor head via MFMA (leaf-independent, reuses ah) ----
    {
        const h8v* Bb8 = (const h8v*)g_Bb;
        f4v tb = (f4v){0.f, 0.f, 0.f, 0.f};
#pragma unroll
        for (int ks = 0; ks < 4; ++ks)
            tb = __builtin_amdgcn_mfma_f32_16x16x32_f16(ah[ks], Bb8[ks * 64 + lane], tb, 0, 0, 0);
        if (c < OUT_DIM) {
#pragma unroll
            for (int rr = 0; rr < 4; ++rr)
                tbS[wave][(g * 4 + rr) * 8 + c] = tb[rr];
        }
    }

    // ---- GEMM + compress, two 128-col halves (acc[8] = 32 AGPRs) ----
    const h8v* Bf8 = (const h8v*)g_Bf;
    float pp[4] = {0.f, 0.f, 0.f, 0.f};
#pragma unroll
    for (int h = 0; h < 2; ++h) {
        f4v acc[8];
#pragma unroll
        for (int nt = 0; nt < 8; ++nt) acc[nt] = (f4v){0.f, 0.f, 0.f, 0.f};
#pragma unroll
        for (int ks = 0; ks < 4; ++ks)
#pragma unroll
            for (int nt = 0; nt < 8; ++nt) {
                h8v b = Bf8[(ks * 16 + h * 8 + nt) * 64 + lane];  // coalesced, L2-hot
                acc[nt] = __builtin_amdgcn_mfma_f32_16x16x32_f16(ah[ks], b, acc[nt], 0, 0, 0);
            }
        // compress: C/D col n = h*128 + nt*16 + c, row m = g*4 + rr.
        // Col 255 is zero-padded in g_Bf -> z=0 contributes 0 to the abs-sum,
        // so no n-guard needed on the accumulation (only on the bp read).
#pragma unroll
        for (int nt = 0; nt < 8; ++nt) {
            const int n = h * 128 + nt * 16 + c;
            const float bpv = (n < INT_NODES) ? bp[n] : 0.f;   // 1KB, L1-hot
            unsigned by = 0;
#pragma unroll
            for (int rr = 0; rr < 4; ++rr) {
                float v = acc[nt][rr] + bpv;
                float av = fabsf(v);
                pp[rr] += av;
                by |= ((v < 0.f ? 1u : 0u) | (av < AMB_TH ? 2u : 0u)) << (2 * rr);
            }
            sgn[n * 4 + g] = (unsigned char)by;
        }
    }
#pragma unroll
    for (int rr = 0; rr < 4; ++rr) asum[(g * 4 + rr) * 16 + c] = pp[rr];

    // ---- heads-x prefetch (leaf-independent; overlaps traversal chain) ----
    h2v xh[16];
    {
        const float* xr = x + (size_t)(rowbase + (lane >> 2)) * IN_DIM;
        const int kq = lane & 3;
#pragma unroll
        for (int ch = 0; ch < 4; ++ch) {
            const int base = (ch * 4 + kq) * 8;
            float4 v0 = *reinterpret_cast<const float4*>(xr + base);
            float4 v1 = *reinterpret_cast<const float4*>(xr + base + 4);
            xh[ch * 4 + 0] = (h2v){(_Float16)v0.x, (_Float16)v0.y};
            xh[ch * 4 + 1] = (h2v){(_Float16)v0.z, (_Float16)v0.w};
            xh[ch * 4 + 2] = (h2v){(_Float16)v1.x, (_Float16)v1.y};
            xh[ch * 4 + 3] = (h2v){(_Float16)v1.z, (_Float16)v1.w};
        }
    }
    LGKM0();   // sgn/asum/tb visible (same wave)

    // ---- traversal + p*: lanes 0..15, one row each ----
    if (lane < 16) {
        const int r = lane;
        float s = 0.f;
#pragma unroll
        for (int cc = 0; cc < 16; cc += 4) {
            f4v v = *reinterpret_cast<f4v*>(&asum[r * 16 + cc]);
            s += (v[0] + v[1]) + (v[2] + v[3]);
        }
        const float fac = s * (1.0f / (float)INT_NODES);
        // p* of argmax leaf: sum_l exp(and_z_l - 8 fac) = (1 + e^{-2 fac})^8.
        const float e = expf(-2.0f * fac);
        const float q = 1.0f + e;
        const float q2 = q * q, q4 = q2 * q2, q8 = q4 * q4;

        int node = 0;
#pragma unroll
        for (int d = 0; d < 8; ++d) {
            unsigned by = sgn[node * 4 + (r >> 2)];
            int code = (int)((by >> ((r & 3) * 2)) & 3u);
            int neg;
            if (code & 2) {          // ~1% of rows: exact sign via fp64, 4 chains
                const float* wr = Wp + node * IN_DIM;
                const float* xrow = x + (size_t)(rowbase + r) * IN_DIM;
                double z0 = 0.0, z1 = 0.0, z2 = 0.0, z3 = 0.0;
                for (int k = 0; k < IN_DIM; k += 4) {
                    float4 wv = *reinterpret_cast<const float4*>(wr + k);
                    float4 xv = *reinterpret_cast<const float4*>(xrow + k);
                    z0 = fma((double)wv.x, (double)xv.x, z0);
                    z1 = fma((double)wv.y, (double)xv.y, z1);
                    z2 = fma((double)wv.z, (double)xv.z, z2);
                    z3 = fma((double)wv.w, (double)xv.w, z3);
                }
                double zd = ((z0 + z1) + (z2 + z3)) + (double)bp[node];
                neg = (zd < 0.0) ? 1 : 0;
            } else {
                neg = code & 1;
            }
            node = 2 * node + 1 + neg;
        }
        psS[wave][r] = 1.0f / q8;
        lfS[wave][r] = node - INT_NODES;
    }
    LGKM0();

    // ---- heads: lane = (row r, K-quarter kq); fp16 gather + fdot2.
    //      Chunk (ch*4+kq): 4 kq lanes cover one 64B line of the 2KB slice. ----
    {
        const int r = lane >> 2, kq = lane & 3;
        const int leaf = lfS[wave][r];
        const _Float16* wl = g_Wh + (size_t)leaf * 1024;
        float hp[8];
#pragma unroll
        for (int o = 0; o < 8; ++o) hp[o] = 0.f;
#pragma unroll
        for (int ch = 0; ch < 4; ++ch) {
            const int base = (ch * 4 + kq) * 8;
            h2v x0 = xh[ch * 4 + 0], x1 = xh[ch * 4 + 1];
            h2v x2 = xh[ch * 4 + 2], x3 = xh[ch * 4 + 3];
#pragma unroll
            for (int o = 0; o < 8; ++o) {
                h8v w8 = *reinterpret_cast<const h8v*>(wl + o * IN_DIM + base);
                h2v w0 = {w8[0], w8[1]}, w1 = {w8[2], w8[3]};
                h2v w2 = {w8[4], w8[5]}, w3 = {w8[6], w8[7]};
                hp[o] = fdot2(w0, x0, hp[o]);
                hp[o] = fdot2(w1, x1, hp[o]);
                hp[o] = fdot2(w2, x2, hp[o]);
                hp[o] = fdot2(w3, x3, hp[o]);
            }
        }
#pragma unroll
        for (int o = 0; o < 8; ++o)
            hd[r * 36 + o * 4 + kq] = hp[o];
    }
    LGKM0();

    // ---- final reduce + stores: lane = (row r, o-pair op) ----
    {
        const int r = lane >> 2, op = lane & 3, o0 = op * 2;
        const float ps = psS[wave][r];
        f4v a = *reinterpret_cast<f4v*>(&hd[r * 36 + o0 * 4]);
        f4v b = *reinterpret_cast<f4v*>(&hd[r * 36 + o0 * 4 + 4]);
        float2 ov;
        ov.x = ps * ((a[0] + a[1]) + (a[2] + a[3])) + tbS[wave][r * 8 + o0];
        ov.y = ps * ((b[0] + b[1]) + (b[2] + b[3])) + tbS[wave][r * 8 + o0 + 1];
        const size_t ob = (size_t)(rowbase + r) * OUT_DIM + o0;
        *reinterpret_cast<float2*>(out + ob) = ov;
        const int leaf = lfS[wave][r];
        float2 sv;
        sv.x = fminf(fmaxf(ps * stds[leaf * OUT_DIM + o0],     -20.0f), 2.0f);
        sv.y = fminf(fmaxf(ps * stds[leaf * OUT_DIM + o0 + 1], -20.0f), 2.0f);
        *reinterpret_cast<float2*>(stdo + ob) = sv;
    }
}

extern "C" void kernel_launch(void* const* d_in, const int* in_sizes, int n_in,
                              void* d_out, int out_size, void* d_ws, size_t ws_size,
                              hipStream_t stream) {
    const float* x    = (const float*)d_in[0];
    const float* Wp   = (const float*)d_in[1];
    const float* bp   = (const float*)d_in[2];
    // d_in[3] = Wand -- folded into the traversal, unused.
    const float* Wor  = (const float*)d_in[4];
    const float* bor  = (const float*)d_in[5];
    const float* stds = (const float*)d_in[6];
    float* out = (float*)d_out;
    (void)d_ws; (void)ws_size;  // ws poison is unconditional (R1); ws unused

    prep<<<200, 256, 0, stream>>>(Wor, Wp, bor);
    dgt_main<<<BATCH / 64, 256, 0, stream>>>(x, Wp, bp, stds,
                                             out, out + (size_t)BATCH * OUT_DIM);
}

// Round 4
// 111.106 us; speedup vs baseline: 1.0481x; 1.0124x over previous
//
#include <hip/hip_runtime.h>

#define BATCH 65536
#define IN_DIM 128
#define INT_NODES 255
#define LEAF 256
#define OUT_DIM 8
#define AMB_TH 1.5e-3f  // fp16-GEMM z error ~3e-4 RMS; ~5-sigma guard band

typedef float    f4v __attribute__((ext_vector_type(4)));
typedef _Float16 h8v __attribute__((ext_vector_type(8)));
typedef _Float16 h2v __attribute__((ext_vector_type(2)));

#define LGKM0() __asm__ volatile("s_waitcnt lgkmcnt(0)" ::: "memory")

// Static module scratch (580 KB). d_ws unused: harness poisons the 256 MiB
// arena unconditionally (R1 experiment).
// R2 lesson: M-replication (32-row waves) regressed — VGPR crossed 128,
// occupancy halved. R3 counters: dgt_main 47.7us, all pipes <15% busy,
// ~1 MB/CU of B-frag L2 reads = the dominant traffic. This version stages
// g_Bf into LDS once per BLOCK (4x less B traffic, zero extra VGPR for
// accumulators) with counted-vmcnt double-buffering.
__device__ __align__(16) _Float16 g_Wh[LEAF * 1024];  // 512 KB fp16 Wor_t
__device__ __align__(16) _Float16 g_Bf[32768];        // 64 KB Wp B-frags
__device__ __align__(16) _Float16 g_Bb[2048];         // 4 KB bor B-frag

__device__ __forceinline__ float fdot2(h2v a, h2v b, float c) {
#if __has_builtin(__builtin_amdgcn_fdot2)
    return __builtin_amdgcn_fdot2(a, b, c, false);
#else
    return c + (float)a[0] * (float)b[0] + (float)a[1] * (float)b[1];
#endif
}

// Prepass: blocks [0,64) LDS-tiled transpose Wor -> g_Wh fp16 [l][o*128+i];
// blocks [64,192) Wp -> fp16 B-frags; blocks [192,200) bor -> fp16 B-frag.
__global__ __launch_bounds__(256) void prep(const float* __restrict__ Wor,
                                            const float* __restrict__ Wp,
                                            const float* __restrict__ bor) {
    if (blockIdx.x < 64) {
        __shared__ float t[64][65];
        const int rt = blockIdx.x >> 2, ct = blockIdx.x & 3;  // 16 x 4 tiles of 64x64
        const int r0 = rt * 64, c0 = ct * 64;
        const int tx = threadIdx.x & 63, ty = threadIdx.x >> 6;
#pragma unroll
        for (int p = 0; p < 16; ++p) {
            int r = ty + p * 4;
            t[r][tx] = Wor[(size_t)(r0 + r) * 256 + c0 + tx];     // coalesced
        }
        __syncthreads();
#pragma unroll
        for (int p = 0; p < 16; ++p) {
            int r = ty + p * 4;
            g_Wh[(size_t)(c0 + r) * 1024 + r0 + tx] = (_Float16)t[tx][r];  // coalesced
        }
    } else if (blockIdx.x < 192) {
        // B-frag (16x16x32): B[k=ks*32+(lane>>4)*8+j][n=ntg*16+(lane&15)],
        // slot = ((ks*16+ntg)*64+lane)*8+j.
        int slot = (blockIdx.x - 64) * 256 + threadIdx.x;   // 32768
        int j    = slot & 7;
        int lane = (slot >> 3) & 63;
        int ntg  = (slot >> 9) & 15;
        int ks   = slot >> 13;
        int n = ntg * 16 + (lane & 15);
        int k = ks * 32 + (lane >> 4) * 8 + j;
        float v = (n < INT_NODES) ? Wp[n * IN_DIM + k] : 0.f;
        g_Bf[slot] = (_Float16)v;
    } else {
        // bor B-frag: one 16-col tile (cols 0..7 = outputs), slot=(ks*64+lane)*8+j
        int slot = (blockIdx.x - 192) * 256 + threadIdx.x;  // 2048
        int j    = slot & 7;
        int lane = (slot >> 3) & 63;
        int ks   = slot >> 9;
        int o = lane & 15;
        int k = ks * 32 + (lane >> 4) * 8 + j;
        float v = (o < OUT_DIM) ? bor[o * IN_DIM + k] : 0.f;
        g_Bb[slot] = (_Float16)v;
    }
}

// Stage one 8 KB (h,ks)-chunk of g_Bf into stageS[buf]. Wave w loads its
// 2 nt-rows (2 KB) via global_load_lds: LDS dest = wave-uniform base +
// lane*16 (linear), global src = per-lane, both contiguous -> coalesced.
#define STAGE(chunk, buf) do {                                                  \
    const int h_ = (chunk) >> 2, ks_ = (chunk) & 3;                             \
    const int nt0_ = wave * 2;                                                  \
    const _Float16* g0_ = g_Bf + (size_t)(((ks_ * 16 + h_ * 8 + nt0_) * 64 + lane) * 8); \
    const _Float16* g1_ = g0_ + 64 * 8;                                         \
    __builtin_amdgcn_global_load_lds(                                           \
        (const __attribute__((address_space(1))) void*)g0_,                     \
        (__attribute__((address_space(3))) void*)&stageS[(buf)][nt0_ * 512],    \
        16, 0, 0);                                                              \
    __builtin_amdgcn_global_load_lds(                                           \
        (const __attribute__((address_space(1))) void*)g1_,                     \
        (__attribute__((address_space(3))) void*)&stageS[(buf)][(nt0_ + 1) * 512], \
        16, 0, 0);                                                              \
} while (0)

// Fused main. Wave = 16 rows x 256 nodes. GEMM B-tiles staged block-wide in
// LDS (double-buffered 8 KB chunks, counted vmcnt + raw s_barrier — no
// __syncthreads, which would drain vmcnt(0)). Post-GEMM phases are
// barrier-free/wave-private so waves decorrelate their latency stalls.
__global__ __launch_bounds__(256, 4) void dgt_main(
    const float* __restrict__ x, const float* __restrict__ Wp,
    const float* __restrict__ bp, const float* __restrict__ stds,
    float* __restrict__ out, float* __restrict__ stdo) {

    __shared__ __align__(16) _Float16 stageS[2][4096];  // 16 KB B double-buffer
    __shared__ unsigned char sgnS[4][LEAF * 4];  // [wave][n*4+g]: codes rows g*4+rr
    __shared__ float asumS[4][16 * 16];          // [wave][row*16 + c]
    __shared__ float hdS[4][16 * 36];            // [wave][r*36 + o*4 + kq]
    __shared__ float tbS[4][16 * 8];             // [wave][r*8 + o]: <bor,x>
    __shared__ float psS[4][16];
    __shared__ int   lfS[4][16];

    const int tid  = threadIdx.x;
    const int wave = tid >> 6;
    const int lane = tid & 63;
    const int c = lane & 15;
    const int g = lane >> 4;
    const int rowbase = blockIdx.x * 64 + wave * 16;

    unsigned char* sgn = sgnS[wave];
    float* asum = asumS[wave];
    float* hd = hdS[wave];

    // ---- bp preload to registers (16 VGPR): keeps the counted-vmcnt GEMM
    //      region free of stray VMEM ops. Static indexing only (rule #20). ----
    float bpv[2][8];
#pragma unroll
    for (int h2 = 0; h2 < 2; ++h2)
#pragma unroll
        for (int nt = 0; nt < 8; ++nt) {
            const int n = h2 * 128 + nt * 16 + c;
            bpv[h2][nt] = (n < INT_NODES) ? bp[n] : 0.f;   // 1KB, L1-hot
        }

    // ---- A-fragments for all 4 k-steps (16 VGPRs) ----
    h8v ah[4];
    {
        const float* xb = x + (size_t)(rowbase + c) * IN_DIM;
#pragma unroll
        for (int ks = 0; ks < 4; ++ks) {
            const float* p = xb + ks * 32 + g * 8;
            float4 v0 = *reinterpret_cast<const float4*>(p);
            float4 v1 = *reinterpret_cast<const float4*>(p + 4);
            h8v a;
            a[0] = (_Float16)v0.x; a[1] = (_Float16)v0.y;
            a[2] = (_Float16)v0.z; a[3] = (_Float16)v0.w;
            a[4] = (_Float16)v1.x; a[5] = (_Float16)v1.y;
            a[6] = (_Float16)v1.z; a[7] = (_Float16)v1.w;
            ah[ks] = a;
        }
    }

    // ---- bor head via MFMA (leaf-independent, reuses ah) ----
    {
        const h8v* Bb8 = (const h8v*)g_Bb;
        f4v tb = (f4v){0.f, 0.f, 0.f, 0.f};
#pragma unroll
        for (int ks = 0; ks < 4; ++ks)
            tb = __builtin_amdgcn_mfma_f32_16x16x32_f16(ah[ks], Bb8[ks * 64 + lane], tb, 0, 0, 0);
        if (c < OUT_DIM) {
#pragma unroll
            for (int rr = 0; rr < 4; ++rr)
                tbS[wave][(g * 4 + rr) * 8 + c] = tb[rr];
        }
    }

    // ---- GEMM pipeline: 8 chunks (h=s>>2, ks=s&3), LDS double-buffer.
    //      vmcnt ledger: at step-s wait, outstanding = stage(s)[2] +
    //      stage(s+1)[2] -> vmcnt(2) drains stage(s); s=7 -> vmcnt(0). ----
    float pp[4] = {0.f, 0.f, 0.f, 0.f};
    f4v acc[8];
    __asm__ volatile("s_waitcnt vmcnt(0)" ::: "memory");   // clean slate
    STAGE(0, 0);
#pragma unroll
    for (int s = 0; s < 8; ++s) {
        const int h = s >> 2, ks = s & 3;
        if (s + 1 < 8) STAGE(s + 1, (s + 1) & 1);   // other buffer: safe, its
                                                    // chunk was consumed at s-1
        if (s < 7) __asm__ volatile("s_waitcnt vmcnt(2)" ::: "memory");
        else       __asm__ volatile("s_waitcnt vmcnt(0)" ::: "memory");
        __builtin_amdgcn_s_barrier();               // all waves' slices landed
        if (ks == 0) {
#pragma unroll
            for (int nt = 0; nt < 8; ++nt) acc[nt] = (f4v){0.f, 0.f, 0.f, 0.f};
        }
        const h8v* bufp = (const h8v*)stageS[s & 1];
#pragma unroll
        for (int nt = 0; nt < 8; ++nt)
            acc[nt] = __builtin_amdgcn_mfma_f32_16x16x32_f16(ah[ks], bufp[nt * 64 + lane], acc[nt], 0, 0, 0);
        if (ks == 3) {
            // compress: C/D col n = h*128 + nt*16 + c, row m = g*4 + rr.
            // Col 255 zero-padded in g_Bf -> contributes 0 to abs-sum.
#pragma unroll
            for (int nt = 0; nt < 8; ++nt) {
                const int n = h * 128 + nt * 16 + c;
                const float bpvv = bpv[h][nt];
                unsigned by = 0;
#pragma unroll
                for (int rr = 0; rr < 4; ++rr) {
                    float v = acc[nt][rr] + bpvv;
                    float av = fabsf(v);
                    pp[rr] += av;
                    by |= ((v < 0.f ? 1u : 0u) | (av < AMB_TH ? 2u : 0u)) << (2 * rr);
                }
                sgn[n * 4 + g] = (unsigned char)by;
            }
        }
        __asm__ volatile("s_waitcnt lgkmcnt(0)" ::: "memory");  // ds_reads done
        __builtin_amdgcn_s_barrier();               // before buffer reuse
    }
#pragma unroll
    for (int rr = 0; rr < 4; ++rr) asum[(g * 4 + rr) * 16 + c] = pp[rr];

    // ---- heads-x prefetch (leaf-independent; overlaps traversal chain) ----
    h2v xh[16];
    {
        const float* xr = x + (size_t)(rowbase + (lane >> 2)) * IN_DIM;
        const int kq = lane & 3;
#pragma unroll
        for (int ch = 0; ch < 4; ++ch) {
            const int base = (ch * 4 + kq) * 8;
            float4 v0 = *reinterpret_cast<const float4*>(xr + base);
            float4 v1 = *reinterpret_cast<const float4*>(xr + base + 4);
            xh[ch * 4 + 0] = (h2v){(_Float16)v0.x, (_Float16)v0.y};
            xh[ch * 4 + 1] = (h2v){(_Float16)v0.z, (_Float16)v0.w};
            xh[ch * 4 + 2] = (h2v){(_Float16)v1.x, (_Float16)v1.y};
            xh[ch * 4 + 3] = (h2v){(_Float16)v1.z, (_Float16)v1.w};
        }
    }
    LGKM0();   // sgn/asum/tb visible (same wave)

    // ---- traversal + p*: lanes 0..15, one row each ----
    if (lane < 16) {
        const int r = lane;
        float s = 0.f;
#pragma unroll
        for (int cc = 0; cc < 16; cc += 4) {
            f4v v = *reinterpret_cast<f4v*>(&asum[r * 16 + cc]);
            s += (v[0] + v[1]) + (v[2] + v[3]);
        }
        const float fac = s * (1.0f / (float)INT_NODES);
        // p* of argmax leaf: sum_l exp(and_z_l - 8 fac) = (1 + e^{-2 fac})^8.
        const float e = expf(-2.0f * fac);
        const float q = 1.0f + e;
        const float q2 = q * q, q4 = q2 * q2, q8 = q4 * q4;

        int node = 0;
#pragma unroll
        for (int d = 0; d < 8; ++d) {
            unsigned by = sgn[node * 4 + (r >> 2)];
            int code = (int)((by >> ((r & 3) * 2)) & 3u);
            int neg;
            if (code & 2) {          // ~1% of rows: exact sign via fp64, 4 chains
                const float* wr = Wp + node * IN_DIM;
                const float* xrow = x + (size_t)(rowbase + r) * IN_DIM;
                double z0 = 0.0, z1 = 0.0, z2 = 0.0, z3 = 0.0;
                for (int k = 0; k < IN_DIM; k += 4) {
                    float4 wv = *reinterpret_cast<const float4*>(wr + k);
                    float4 xv = *reinterpret_cast<const float4*>(xrow + k);
                    z0 = fma((double)wv.x, (double)xv.x, z0);
                    z1 = fma((double)wv.y, (double)xv.y, z1);
                    z2 = fma((double)wv.z, (double)xv.z, z2);
                    z3 = fma((double)wv.w, (double)xv.w, z3);
                }
                double zd = ((z0 + z1) + (z2 + z3)) + (double)bp[node];
                neg = (zd < 0.0) ? 1 : 0;
            } else {
                neg = code & 1;
            }
            node = 2 * node + 1 + neg;
        }
        psS[wave][r] = 1.0f / q8;
        lfS[wave][r] = node - INT_NODES;
    }
    LGKM0();

    // ---- heads: lane = (row r, K-quarter kq); fp16 gather + fdot2.
    //      Chunk (ch*4+kq): 4 kq lanes cover one 64B line of the 2KB slice. ----
    {
        const int r = lane >> 2, kq = lane & 3;
        const int leaf = lfS[wave][r];
        const _Float16* wl = g_Wh + (size_t)leaf * 1024;
        float hp[8];
#pragma unroll
        for (int o = 0; o < 8; ++o) hp[o] = 0.f;
#pragma unroll
        for (int ch = 0; ch < 4; ++ch) {
            const int base = (ch * 4 + kq) * 8;
            h2v x0 = xh[ch * 4 + 0], x1 = xh[ch * 4 + 1];
            h2v x2 = xh[ch * 4 + 2], x3 = xh[ch * 4 + 3];
#pragma unroll
            for (int o = 0; o < 8; ++o) {
                h8v w8 = *reinterpret_cast<const h8v*>(wl + o * IN_DIM + base);
                h2v w0 = {w8[0], w8[1]}, w1 = {w8[2], w8[3]};
                h2v w2 = {w8[4], w8[5]}, w3 = {w8[6], w8[7]};
                hp[o] = fdot2(w0, x0, hp[o]);
                hp[o] = fdot2(w1, x1, hp[o]);
                hp[o] = fdot2(w2, x2, hp[o]);
                hp[o] = fdot2(w3, x3, hp[o]);
            }
        }
#pragma unroll
        for (int o = 0; o < 8; ++o)
            hd[r * 36 + o * 4 + kq] = hp[o];
    }
    LGKM0();

    // ---- final reduce + stores: lane = (row r, o-pair op) ----
    {
        const int r = lane >> 2, op = lane & 3, o0 = op * 2;
        const float ps = psS[wave][r];
        f4v a = *reinterpret_cast<f4v*>(&hd[r * 36 + o0 * 4]);
        f4v b = *reinterpret_cast<f4v*>(&hd[r * 36 + o0 * 4 + 4]);
        float2 ov;
        ov.x = ps * ((a[0] + a[1]) + (a[2] + a[3])) + tbS[wave][r * 8 + o0];
        ov.y = ps * ((b[0] + b[1]) + (b[2] + b[3])) + tbS[wave][r * 8 + o0 + 1];
        const size_t ob = (size_t)(rowbase + r) * OUT_DIM + o0;
        *reinterpret_cast<float2*>(out + ob) = ov;
        const int leaf = lfS[wave][r];
        float2 sv;
        sv.x = fminf(fmaxf(ps * stds[leaf * OUT_DIM + o0],     -20.0f), 2.0f);
        sv.y = fminf(fmaxf(ps * stds[leaf * OUT_DIM + o0 + 1], -20.0f), 2.0f);
        *reinterpret_cast<float2*>(stdo + ob) = sv;
    }
}

extern "C" void kernel_launch(void* const* d_in, const int* in_sizes, int n_in,
                              void* d_out, int out_size, void* d_ws, size_t ws_size,
                              hipStream_t stream) {
    const float* x    = (const float*)d_in[0];
    const float* Wp   = (const float*)d_in[1];
    const float* bp   = (const float*)d_in[2];
    // d_in[3] = Wand -- folded into the traversal, unused.
    const float* Wor  = (const float*)d_in[4];
    const float* bor  = (const float*)d_in[5];
    const float* stds = (const float*)d_in[6];
    float* out = (float*)d_out;
    (void)d_ws; (void)ws_size;  // ws poison is unconditional (R1); ws unused

    prep<<<200, 256, 0, stream>>>(Wor, Wp, bor);
    dgt_main<<<BATCH / 64, 256, 0, stream>>>(x, Wp, bp, stds,
                                             out, out + (size_t)BATCH * OUT_DIM);
}

// Round 5
// 110.234 us; speedup vs baseline: 1.0564x; 1.0079x over previous
//
#include <hip/hip_runtime.h>

#define BATCH 65536
#define IN_DIM 128
#define INT_NODES 255
#define LEAF 256
#define OUT_DIM 8
#define AMB_TH 1.5e-3f  // fp16-GEMM z error ~3e-4 RMS; ~5-sigma guard band

typedef float    f4v __attribute__((ext_vector_type(4)));
typedef _Float16 h8v __attribute__((ext_vector_type(8)));
typedef _Float16 h2v __attribute__((ext_vector_type(2)));

#define LGKM0() __asm__ volatile("s_waitcnt lgkmcnt(0)" ::: "memory")

// Static module scratch (580 KB). d_ws unused: harness poisons the 256 MiB
// arena unconditionally (R1 experiment).
// R2 lesson: M-replication regressed (VGPR >128, occupancy cliff).
// R4: block-wide LDS staging of g_Bf cut dgt_main 47.7 -> ~40us.
// R5 theory: R3's OccupancyPercent=16.7% (5.4 waves/CU avg vs 16 resident)
// = straggler-tail signature. Suspect: the rolled 32-trip fp64 rescue loop
// (~300cy L2 latency x 32, serialized) -> #pragma unroll 4 pipelines the
// loads (~4x fewer latency stalls), bit-identical accumulation.
__device__ __align__(16) _Float16 g_Wh[LEAF * 1024];  // 512 KB fp16 Wor_t
__device__ __align__(16) _Float16 g_Bf[32768];        // 64 KB Wp B-frags
__device__ __align__(16) _Float16 g_Bb[2048];         // 4 KB bor B-frag

__device__ __forceinline__ float fdot2(h2v a, h2v b, float c) {
#if __has_builtin(__builtin_amdgcn_fdot2)
    return __builtin_amdgcn_fdot2(a, b, c, false);
#else
    return c + (float)a[0] * (float)b[0] + (float)a[1] * (float)b[1];
#endif
}

// Prepass: blocks [0,64) LDS-tiled transpose Wor -> g_Wh fp16 [l][o*128+i];
// blocks [64,192) Wp -> fp16 B-frags; blocks [192,200) bor -> fp16 B-frag.
__global__ __launch_bounds__(256) void prep(const float* __restrict__ Wor,
                                            const float* __restrict__ Wp,
                                            const float* __restrict__ bor) {
    if (blockIdx.x < 64) {
        __shared__ float t[64][65];
        const int rt = blockIdx.x >> 2, ct = blockIdx.x & 3;  // 16 x 4 tiles of 64x64
        const int r0 = rt * 64, c0 = ct * 64;
        const int tx = threadIdx.x & 63, ty = threadIdx.x >> 6;
#pragma unroll
        for (int p = 0; p < 16; ++p) {
            int r = ty + p * 4;
            t[r][tx] = Wor[(size_t)(r0 + r) * 256 + c0 + tx];     // coalesced
        }
        __syncthreads();
#pragma unroll
        for (int p = 0; p < 16; ++p) {
            int r = ty + p * 4;
            g_Wh[(size_t)(c0 + r) * 1024 + r0 + tx] = (_Float16)t[tx][r];  // coalesced
        }
    } else if (blockIdx.x < 192) {
        // B-frag (16x16x32): B[k=ks*32+(lane>>4)*8+j][n=ntg*16+(lane&15)],
        // slot = ((ks*16+ntg)*64+lane)*8+j.
        int slot = (blockIdx.x - 64) * 256 + threadIdx.x;   // 32768
        int j    = slot & 7;
        int lane = (slot >> 3) & 63;
        int ntg  = (slot >> 9) & 15;
        int ks   = slot >> 13;
        int n = ntg * 16 + (lane & 15);
        int k = ks * 32 + (lane >> 4) * 8 + j;
        float v = (n < INT_NODES) ? Wp[n * IN_DIM + k] : 0.f;
        g_Bf[slot] = (_Float16)v;
    } else {
        // bor B-frag: one 16-col tile (cols 0..7 = outputs), slot=(ks*64+lane)*8+j
        int slot = (blockIdx.x - 192) * 256 + threadIdx.x;  // 2048
        int j    = slot & 7;
        int lane = (slot >> 3) & 63;
        int ks   = slot >> 9;
        int o = lane & 15;
        int k = ks * 32 + (lane >> 4) * 8 + j;
        float v = (o < OUT_DIM) ? bor[o * IN_DIM + k] : 0.f;
        g_Bb[slot] = (_Float16)v;
    }
}

// Stage one 8 KB (h,ks)-chunk of g_Bf into stageS[buf]. Wave w loads its
// 2 nt-rows (2 KB) via global_load_lds: LDS dest = wave-uniform base +
// lane*16 (linear), global src = per-lane, both contiguous -> coalesced.
#define STAGE(chunk, buf) do {                                                  \
    const int h_ = (chunk) >> 2, ks_ = (chunk) & 3;                             \
    const int nt0_ = wave * 2;                                                  \
    const _Float16* g0_ = g_Bf + (size_t)(((ks_ * 16 + h_ * 8 + nt0_) * 64 + lane) * 8); \
    const _Float16* g1_ = g0_ + 64 * 8;                                         \
    __builtin_amdgcn_global_load_lds(                                           \
        (const __attribute__((address_space(1))) void*)g0_,                     \
        (__attribute__((address_space(3))) void*)&stageS[(buf)][nt0_ * 512],    \
        16, 0, 0);                                                              \
    __builtin_amdgcn_global_load_lds(                                           \
        (const __attribute__((address_space(1))) void*)g1_,                     \
        (__attribute__((address_space(3))) void*)&stageS[(buf)][(nt0_ + 1) * 512], \
        16, 0, 0);                                                              \
} while (0)

// Fused main. Wave = 16 rows x 256 nodes. GEMM B-tiles staged block-wide in
// LDS (double-buffered 8 KB chunks, counted vmcnt + raw s_barrier). Post-GEMM
// phases are barrier-free/wave-private so waves decorrelate latency stalls.
__global__ __launch_bounds__(256, 4) void dgt_main(
    const float* __restrict__ x, const float* __restrict__ Wp,
    const float* __restrict__ bp, const float* __restrict__ stds,
    float* __restrict__ out, float* __restrict__ stdo) {

    __shared__ __align__(16) _Float16 stageS[2][4096];  // 16 KB B double-buffer
    __shared__ unsigned char sgnS[4][LEAF * 4];  // [wave][n*4+g]: codes rows g*4+rr
    __shared__ float asumS[4][16 * 16];          // [wave][row*16 + c]
    __shared__ float hdS[4][16 * 36];            // [wave][r*36 + o*4 + kq]
    __shared__ float tbS[4][16 * 8];             // [wave][r*8 + o]: <bor,x>
    __shared__ float psS[4][16];
    __shared__ int   lfS[4][16];

    const int tid  = threadIdx.x;
    const int wave = tid >> 6;
    const int lane = tid & 63;
    const int c = lane & 15;
    const int g = lane >> 4;
    const int rowbase = blockIdx.x * 64 + wave * 16;

    unsigned char* sgn = sgnS[wave];
    float* asum = asumS[wave];
    float* hd = hdS[wave];

    // ---- bp preload to registers (16 VGPR): keeps the counted-vmcnt GEMM
    //      region free of stray VMEM ops. Static indexing only (rule #20). ----
    float bpv[2][8];
#pragma unroll
    for (int h2 = 0; h2 < 2; ++h2)
#pragma unroll
        for (int nt = 0; nt < 8; ++nt) {
            const int n = h2 * 128 + nt * 16 + c;
            bpv[h2][nt] = (n < INT_NODES) ? bp[n] : 0.f;   // 1KB, L1-hot
        }

    // ---- A-fragments for all 4 k-steps (16 VGPRs) ----
    h8v ah[4];
    {
        const float* xb = x + (size_t)(rowbase + c) * IN_DIM;
#pragma unroll
        for (int ks = 0; ks < 4; ++ks) {
            const float* p = xb + ks * 32 + g * 8;
            float4 v0 = *reinterpret_cast<const float4*>(p);
            float4 v1 = *reinterpret_cast<const float4*>(p + 4);
            h8v a;
            a[0] = (_Float16)v0.x; a[1] = (_Float16)v0.y;
            a[2] = (_Float16)v0.z; a[3] = (_Float16)v0.w;
            a[4] = (_Float16)v1.x; a[5] = (_Float16)v1.y;
            a[6] = (_Float16)v1.z; a[7] = (_Float16)v1.w;
            ah[ks] = a;
        }
    }

    // ---- bor head via MFMA (leaf-independent, reuses ah) ----
    {
        const h8v* Bb8 = (const h8v*)g_Bb;
        f4v tb = (f4v){0.f, 0.f, 0.f, 0.f};
#pragma unroll
        for (int ks = 0; ks < 4; ++ks)
            tb = __builtin_amdgcn_mfma_f32_16x16x32_f16(ah[ks], Bb8[ks * 64 + lane], tb, 0, 0, 0);
        if (c < OUT_DIM) {
#pragma unroll
            for (int rr = 0; rr < 4; ++rr)
                tbS[wave][(g * 4 + rr) * 8 + c] = tb[rr];
        }
    }

    // ---- GEMM pipeline: 8 chunks (h=s>>2, ks=s&3), LDS double-buffer.
    //      vmcnt ledger: at step-s wait, outstanding = stage(s)[2] +
    //      stage(s+1)[2] -> vmcnt(2) drains stage(s); s=7 -> vmcnt(0). ----
    float pp[4] = {0.f, 0.f, 0.f, 0.f};
    f4v acc[8];
    __asm__ volatile("s_waitcnt vmcnt(0)" ::: "memory");   // clean slate
    STAGE(0, 0);
#pragma unroll
    for (int s = 0; s < 8; ++s) {
        const int h = s >> 2, ks = s & 3;
        if (s + 1 < 8) STAGE(s + 1, (s + 1) & 1);   // other buffer: safe, its
                                                    // chunk was consumed at s-1
        if (s < 7) __asm__ volatile("s_waitcnt vmcnt(2)" ::: "memory");
        else       __asm__ volatile("s_waitcnt vmcnt(0)" ::: "memory");
        __builtin_amdgcn_s_barrier();               // all waves' slices landed
        if (ks == 0) {
#pragma unroll
            for (int nt = 0; nt < 8; ++nt) acc[nt] = (f4v){0.f, 0.f, 0.f, 0.f};
        }
        const h8v* bufp = (const h8v*)stageS[s & 1];
#pragma unroll
        for (int nt = 0; nt < 8; ++nt)
            acc[nt] = __builtin_amdgcn_mfma_f32_16x16x32_f16(ah[ks], bufp[nt * 64 + lane], acc[nt], 0, 0, 0);
        if (ks == 3) {
            // compress: C/D col n = h*128 + nt*16 + c, row m = g*4 + rr.
            // Col 255 zero-padded in g_Bf -> contributes 0 to abs-sum.
#pragma unroll
            for (int nt = 0; nt < 8; ++nt) {
                const int n = h * 128 + nt * 16 + c;
                const float bpvv = bpv[h][nt];
                unsigned by = 0;
#pragma unroll
                for (int rr = 0; rr < 4; ++rr) {
                    float v = acc[nt][rr] + bpvv;
                    float av = fabsf(v);
                    pp[rr] += av;
                    by |= ((v < 0.f ? 1u : 0u) | (av < AMB_TH ? 2u : 0u)) << (2 * rr);
                }
                sgn[n * 4 + g] = (unsigned char)by;
            }
        }
        __asm__ volatile("s_waitcnt lgkmcnt(0)" ::: "memory");  // ds_reads done
        __builtin_amdgcn_s_barrier();               // before buffer reuse
    }
#pragma unroll
    for (int rr = 0; rr < 4; ++rr) asum[(g * 4 + rr) * 16 + c] = pp[rr];

    // ---- heads-x prefetch (leaf-independent; overlaps traversal chain) ----
    h2v xh[16];
    {
        const float* xr = x + (size_t)(rowbase + (lane >> 2)) * IN_DIM;
        const int kq = lane & 3;
#pragma unroll
        for (int ch = 0; ch < 4; ++ch) {
            const int base = (ch * 4 + kq) * 8;
            float4 v0 = *reinterpret_cast<const float4*>(xr + base);
            float4 v1 = *reinterpret_cast<const float4*>(xr + base + 4);
            xh[ch * 4 + 0] = (h2v){(_Float16)v0.x, (_Float16)v0.y};
            xh[ch * 4 + 1] = (h2v){(_Float16)v0.z, (_Float16)v0.w};
            xh[ch * 4 + 2] = (h2v){(_Float16)v1.x, (_Float16)v1.y};
            xh[ch * 4 + 3] = (h2v){(_Float16)v1.z, (_Float16)v1.w};
        }
    }
    LGKM0();   // sgn/asum/tb visible (same wave)

    // ---- traversal + p*: lanes 0..15, one row each ----
    if (lane < 16) {
        const int r = lane;
        float s = 0.f;
#pragma unroll
        for (int cc = 0; cc < 16; cc += 4) {
            f4v v = *reinterpret_cast<f4v*>(&asum[r * 16 + cc]);
            s += (v[0] + v[1]) + (v[2] + v[3]);
        }
        const float fac = s * (1.0f / (float)INT_NODES);
        // p* of argmax leaf: sum_l exp(and_z_l - 8 fac) = (1 + e^{-2 fac})^8.
        const float e = expf(-2.0f * fac);
        const float q = 1.0f + e;
        const float q2 = q * q, q4 = q2 * q2, q8 = q4 * q4;

        int node = 0;
#pragma unroll
        for (int d = 0; d < 8; ++d) {
            unsigned by = sgn[node * 4 + (r >> 2)];
            int code = (int)((by >> ((r & 3) * 2)) & 3u);
            int neg;
            if (code & 2) {
                // Rare (~1% of rows) exact-sign rescue via fp64, 4 chains.
                // R5: unroll 4 -> 8 independent float4 loads in flight per
                // group (vs 2 rolled): the rolled loop's 32 serialized ~300cy
                // L2 waits were the suspected straggler tail (R3 occupancy
                // signature). Accumulation order unchanged -> bit-identical.
                const float* wr = Wp + node * IN_DIM;
                const float* xrow = x + (size_t)(rowbase + r) * IN_DIM;
                double z0 = 0.0, z1 = 0.0, z2 = 0.0, z3 = 0.0;
#pragma unroll 4
                for (int k = 0; k < IN_DIM; k += 4) {
                    float4 wv = *reinterpret_cast<const float4*>(wr + k);
                    float4 xv = *reinterpret_cast<const float4*>(xrow + k);
                    z0 = fma((double)wv.x, (double)xv.x, z0);
                    z1 = fma((double)wv.y, (double)xv.y, z1);
                    z2 = fma((double)wv.z, (double)xv.z, z2);
                    z3 = fma((double)wv.w, (double)xv.w, z3);
                }
                double zd = ((z0 + z1) + (z2 + z3)) + (double)bp[node];
                neg = (zd < 0.0) ? 1 : 0;
            } else {
                neg = code & 1;
            }
            node = 2 * node + 1 + neg;
        }
        psS[wave][r] = 1.0f / q8;
        lfS[wave][r] = node - INT_NODES;
    }
    LGKM0();

    // ---- heads: lane = (row r, K-quarter kq); fp16 gather + fdot2.
    //      Chunk (ch*4+kq): 4 kq lanes cover one 64B line of the 2KB slice. ----
    {
        const int r = lane >> 2, kq = lane & 3;
        const int leaf = lfS[wave][r];
        const _Float16* wl = g_Wh + (size_t)leaf * 1024;
        float hp[8];
#pragma unroll
        for (int o = 0; o < 8; ++o) hp[o] = 0.f;
#pragma unroll
        for (int ch = 0; ch < 4; ++ch) {
            const int base = (ch * 4 + kq) * 8;
            h2v x0 = xh[ch * 4 + 0], x1 = xh[ch * 4 + 1];
            h2v x2 = xh[ch * 4 + 2], x3 = xh[ch * 4 + 3];
#pragma unroll
            for (int o = 0; o < 8; ++o) {
                h8v w8 = *reinterpret_cast<const h8v*>(wl + o * IN_DIM + base);
                h2v w0 = {w8[0], w8[1]}, w1 = {w8[2], w8[3]};
                h2v w2 = {w8[4], w8[5]}, w3 = {w8[6], w8[7]};
                hp[o] = fdot2(w0, x0, hp[o]);
                hp[o] = fdot2(w1, x1, hp[o]);
                hp[o] = fdot2(w2, x2, hp[o]);
                hp[o] = fdot2(w3, x3, hp[o]);
            }
        }
#pragma unroll
        for (int o = 0; o < 8; ++o)
            hd[r * 36 + o * 4 + kq] = hp[o];
    }
    LGKM0();

    // ---- final reduce + stores: lane = (row r, o-pair op) ----
    {
        const int r = lane >> 2, op = lane & 3, o0 = op * 2;
        const float ps = psS[wave][r];
        f4v a = *reinterpret_cast<f4v*>(&hd[r * 36 + o0 * 4]);
        f4v b = *reinterpret_cast<f4v*>(&hd[r * 36 + o0 * 4 + 4]);
        float2 ov;
        ov.x = ps * ((a[0] + a[1]) + (a[2] + a[3])) + tbS[wave][r * 8 + o0];
        ov.y = ps * ((b[0] + b[1]) + (b[2] + b[3])) + tbS[wave][r * 8 + o0 + 1];
        const size_t ob = (size_t)(rowbase + r) * OUT_DIM + o0;
        *reinterpret_cast<float2*>(out + ob) = ov;
        const int leaf = lfS[wave][r];
        float2 sv;
        sv.x = fminf(fmaxf(ps * stds[leaf * OUT_DIM + o0],     -20.0f), 2.0f);
        sv.y = fminf(fmaxf(ps * stds[leaf * OUT_DIM + o0 + 1], -20.0f), 2.0f);
        *reinterpret_cast<float2*>(stdo + ob) = sv;
    }
}

extern "C" void kernel_launch(void* const* d_in, const int* in_sizes, int n_in,
                              void* d_out, int out_size, void* d_ws, size_t ws_size,
                              hipStream_t stream) {
    const float* x    = (const float*)d_in[0];
    const float* Wp   = (const float*)d_in[1];
    const float* bp   = (const float*)d_in[2];
    // d_in[3] = Wand -- folded into the traversal, unused.
    const float* Wor  = (const float*)d_in[4];
    const float* bor  = (const float*)d_in[5];
    const float* stds = (const float*)d_in[6];
    float* out = (float*)d_out;
    (void)d_ws; (void)ws_size;  // ws poison is unconditional (R1); ws unused

    prep<<<200, 256, 0, stream>>>(Wor, Wp, bor);
    dgt_main<<<BATCH / 64, 256, 0, stream>>>(x, Wp, bp, stds,
                                             out, out + (size_t)BATCH * OUT_DIM);
}